// Round 7
// baseline (304.071 us; speedup 1.0000x reference)
//
#include <hip/hip_runtime.h>
#include <hip/hip_bf16.h>
#include <math.h>

// Router: logits = x@W + b ; softmax; top-2 -> (idx-as-float, gate)
// x: [16384, 2048] f32, W: [2048, 64] f32, b: [64] f32
// out f32: [ntok*2] indices, then [ntok*2] gates.
//
// R7: (a) anti-spill: step loop forced unroll(1) so only one step's W-frags
// (32 VGPR) are live; staging uses non-temporal loads (no L3 dirty-line
// eviction on our critical path). (b) instrumentation: a rep=5 gemm dispatch
// into scratch (>77us -> forces its counters into the top-5 table).

#define DIM 2048
#define NE 64
#define TSTRIDE 2064  // row stride bytes: 512 floats + 16 B pad

typedef __attribute__((ext_vector_type(8))) short short8;
typedef __attribute__((ext_vector_type(4))) float floatx4;

__device__ __forceinline__ short bf16bits(float v) {
  __hip_bfloat16 h = __float2bfloat16(v);
  return *(short*)&h;
}
__device__ __forceinline__ float bf16tof(short s) {
  union { unsigned int u; float f; } c;
  c.u = ((unsigned int)(unsigned short)s) << 16;
  return c.f;
}

// ---- W fragment prep: wf[sg(64)][n(4)][plane(2)][lane(64)] = short8 ----
// B-frag 16x16x32: lane l holds B[k = sg*32 + (l>>4)*8 + j][e = n*16 + (l&15)]
__global__ void wprep_kernel(const float* __restrict__ W, short8* __restrict__ wf) {
  const int s = blockIdx.x >> 2, n = blockIdx.x & 3, l = threadIdx.x;
  const int d0 = s * 32 + (l >> 4) * 8;
  const int e = n * 16 + (l & 15);
  short8 vh, vl;
#pragma unroll
  for (int j = 0; j < 8; ++j) {
    float v = W[(size_t)(d0 + j) * NE + e];
    short h = bf16bits(v);
    vh[j] = h;
    vl[j] = bf16bits(v - bf16tof(h));
  }
  wf[(size_t)((s * 4 + n) * 2 + 0) * 64 + l] = vh;
  wf[(size_t)((s * 4 + n) * 2 + 1) * 64 + l] = vl;
}

// ---- kernel 1: partial GEMM. block (g,s): tokens [g*16,+16), k [s*512,+512)
// rep>1 repeats the whole body (instrumentation only; same result each pass).
__global__ __launch_bounds__(256, 4) void router_gemm(
    const float* __restrict__ x, const short8* __restrict__ wf,
    float* __restrict__ part, int rep) {
  __shared__ alignas(16) char smem[16 * TSTRIDE];  // 33024 B; red overlays it
  const int tid = threadIdx.x, lane = tid & 63, kq = tid >> 6;
  const int g = lane & 15, r4 = lane >> 4;
  const int gblk = blockIdx.x >> 2, s = blockIdx.x & 3;
  const int tok0 = gblk * 16;
  float* red = (float*)smem;

  for (int it = 0; it < rep; ++it) {
    // ---- stage 16 rows x 2 KB (NT loads -> ds_write_b128) ----
    {
      const int row = kq * 4 + r4;
      const float* rp = x + (size_t)(tok0 + row) * DIM + s * 512 + g * 4;
      char* wb = smem + row * TSTRIDE + g * 16;
      floatx4 t[8];
#pragma unroll
      for (int p = 0; p < 8; ++p)
        t[p] = __builtin_nontemporal_load((const floatx4*)(rp + p * 64));
#pragma unroll
      for (int p = 0; p < 8; ++p) *(floatx4*)(wb + p * 256) = t[p];
    }

    floatx4 acc[4];
#pragma unroll
    for (int n = 0; n < 4; ++n) acc[n] = (floatx4){0.f, 0.f, 0.f, 0.f};

    __syncthreads();

    // wave kq computes k-range [kq*128,+128); NOT unrolled (register cap)
#pragma unroll 1
    for (int step = 0; step < 4; ++step) {
      const int sg = s * 16 + kq * 4 + step;  // global 32-k step
      const short8* wp = wf + (size_t)sg * 512;
      short8 Wh[4], Wl[4];
#pragma unroll
      for (int n = 0; n < 4; ++n) {
        Wh[n] = wp[(n * 2 + 0) * 64 + lane];
        Wl[n] = wp[(n * 2 + 1) * 64 + lane];
      }
      // A-frag: m = lane&15 (token), k = step*32 + (lane>>4)*8 + j
      const char* ap = smem + g * TSTRIDE + kq * 512 + step * 128 + r4 * 32;
      floatx4 a0 = *(const floatx4*)ap;
      floatx4 a1 = *(const floatx4*)(ap + 16);
      short8 Ah, Al;
#pragma unroll
      for (int j = 0; j < 4; ++j) {
        short h = bf16bits(a0[j]);
        Ah[j] = h; Al[j] = bf16bits(a0[j] - bf16tof(h));
      }
#pragma unroll
      for (int j = 0; j < 4; ++j) {
        short h = bf16bits(a1[j]);
        Ah[4 + j] = h; Al[4 + j] = bf16bits(a1[j] - bf16tof(h));
      }
#pragma unroll
      for (int n = 0; n < 4; ++n) {
        acc[n] = __builtin_amdgcn_mfma_f32_16x16x32_bf16(Ah, Wh[n], acc[n], 0, 0, 0);
        acc[n] = __builtin_amdgcn_mfma_f32_16x16x32_bf16(Ah, Wl[n], acc[n], 0, 0, 0);
        acc[n] = __builtin_amdgcn_mfma_f32_16x16x32_bf16(Al, Wh[n], acc[n], 0, 0, 0);
      }
    }

    // ---- cross-wave K reduction in LDS (stride 65) ----
    __syncthreads();  // all waves done reading the x tile
#pragma unroll
    for (int n = 0; n < 4; ++n)
#pragma unroll
      for (int r = 0; r < 4; ++r) {
        const int tokl = r4 * 4 + r;  // C/D: row = (lane>>4)*4+reg (token)
        const int e = n * 16 + g;     // C/D: col = lane&15 (expert)
        red[(kq * 16 + tokl) * 65 + e] = acc[n][r];
      }
    __syncthreads();

    // reduce 4 wave-partials -> part[blk][tok*64+e]
    {
      const int tok = tid >> 4, e0 = (tid & 15) * 4;
      floatx4 v = (floatx4){0.f, 0.f, 0.f, 0.f};
#pragma unroll
      for (int k4 = 0; k4 < 4; ++k4)
#pragma unroll
        for (int j = 0; j < 4; ++j) v[j] += red[(k4 * 16 + tok) * 65 + e0 + j];
      __builtin_nontemporal_store(
          v, (floatx4*)(part + (size_t)blockIdx.x * 1024 + tok * 64 + e0));
    }
    __syncthreads();  // red region re-used as x tile next iteration
  }
}

// ---- kernel 2: reduce 4 k-slices + bias -> softmax + top-2 ----
__global__ __launch_bounds__(256) void router_topk(
    const float* __restrict__ part, const float* __restrict__ b,
    float* __restrict__ out, int ntok) {
  const int tid = threadIdx.x;
  const int T = blockIdx.x * 16 + (tid >> 4);
  const int eq = tid & 15, e0 = eq * 4;
  const float* pb = part + (size_t)((T >> 4) * 4) * 1024 + (T & 15) * 64 + e0;
  floatx4 a = (floatx4){0.f, 0.f, 0.f, 0.f};
#pragma unroll
  for (int s = 0; s < 4; ++s) a += *(const floatx4*)(pb + (size_t)s * 1024);
  floatx4 bb = *(const floatx4*)(b + e0);
  float lv[4];
  float v1 = -INFINITY, v2 = -INFINITY;
  int i1 = 0, i2 = 0;
#pragma unroll
  for (int j = 0; j < 4; ++j) {
    float v = a[j] + bb[j];
    lv[j] = v;
    const int e = e0 + j;
    if (v > v1) { v2 = v1; i2 = i1; v1 = v; i1 = e; }
    else if (v > v2) { v2 = v; i2 = e; }
  }
#pragma unroll
  for (int off = 1; off < 16; off <<= 1) {
    float ov1 = __shfl_xor(v1, off, 64); int oi1 = __shfl_xor(i1, off, 64);
    float ov2 = __shfl_xor(v2, off, 64); int oi2 = __shfl_xor(i2, off, 64);
    bool aw = (v1 > ov1) || (v1 == ov1 && i1 < oi1);
    float nv1 = aw ? v1 : ov1; int ni1 = aw ? i1 : oi1;
    float c2v = aw ? ov1 : v1; int c2i = aw ? oi1 : i1;
    float w2v = aw ? v2 : ov2; int w2i = aw ? i2 : oi2;
    bool sw = (w2v > c2v) || (w2v == c2v && w2i < c2i);
    v2 = sw ? w2v : c2v; i2 = sw ? w2i : c2i;
    v1 = nv1; i1 = ni1;
  }
  float se = 0.f;
#pragma unroll
  for (int j = 0; j < 4; ++j) se += __expf(lv[j] - v1);
#pragma unroll
  for (int off = 1; off < 16; off <<= 1) se += __shfl_xor(se, off, 64);
  if (eq == 0) {
    out[T * 2 + 0] = (float)i1;
    out[T * 2 + 1] = (float)i2;
    out[ntok * 2 + T * 2 + 0] = 1.0f / se;
    out[ntok * 2 + T * 2 + 1] = __expf(v2 - v1) / se;
  }
}

extern "C" void kernel_launch(void* const* d_in, const int* in_sizes, int n_in,
                              void* d_out, int out_size, void* d_ws, size_t ws_size,
                              hipStream_t stream) {
  const float* x = (const float*)d_in[0];
  const float* W = (const float*)d_in[1];
  const float* b = (const float*)d_in[2];
  float* out = (float*)d_out;
  const int ntok = in_sizes[0] / DIM;                     // 16384
  short8* wf = (short8*)d_ws;                             // 512 KB W frags
  float* part = (float*)((char*)d_ws + (1u << 20));       // 16.8 MB partials
  float* part2 = (float*)((char*)d_ws + (256u << 20));    // scratch (inst)

  wprep_kernel<<<256, 64, 0, stream>>>(W, wf);
  // instrumented dispatch: rep=5 forces >77us so its counters reach top-5
  router_gemm<<<(ntok / 16) * 4, 256, 0, stream>>>(x, wf, part2, 5);
  // real pipeline
  router_gemm<<<(ntok / 16) * 4, 256, 0, stream>>>(x, wf, part, 1);
  router_topk<<<ntok / 16, 256, 0, stream>>>(part, b, out, ntok);
}

// Round 8
// 199.877 us; speedup vs baseline: 1.5213x; 1.5213x over previous
//
#include <hip/hip_runtime.h>
#include <hip/hip_bf16.h>
#include <math.h>

// Router: logits = x@W + b ; softmax; top-2 -> (idx-as-float, gate)
// x: [16384, 2048] f32, W: [2048, 64] f32, b: [64] f32
// out f32: [ntok*2] indices, then [ntok*2] gates.
//
// R8: fused single-pass. Block = 16 tokens x full 2048 k (4 chunks of 512),
// bf16 hi/lo split MFMA (3 products), acc carried across chunks in AGPR/VGPR.
// Compute loop identical to R7's 24us/pass structure (unroll(1), NT loads).
// Epilogue: b128 cross-wave reduce [kq][e][tok] + in-block softmax/top-2.
// No partials buffer, no second GEMM-side kernel.

#define DIM 2048
#define NE 64
#define TSTRIDE 2064  // x-tile row stride bytes: 512 floats + 16 B pad

typedef __attribute__((ext_vector_type(8))) short short8;
typedef __attribute__((ext_vector_type(4))) float floatx4;

__device__ __forceinline__ short bf16bits(float v) {
  __hip_bfloat16 h = __float2bfloat16(v);
  return *(short*)&h;
}
__device__ __forceinline__ float bf16tof(short s) {
  union { unsigned int u; float f; } c;
  c.u = ((unsigned int)(unsigned short)s) << 16;
  return c.f;
}

// ---- W fragment prep: wf[sg(64)][n(4)][plane(2)][lane(64)] = short8 ----
// B-frag 16x16x32: lane l holds B[k = sg*32 + (l>>4)*8 + j][e = n*16 + (l&15)]
__global__ void wprep_kernel(const float* __restrict__ W, short8* __restrict__ wf) {
  const int s = blockIdx.x >> 2, n = blockIdx.x & 3, l = threadIdx.x;
  const int d0 = s * 32 + (l >> 4) * 8;
  const int e = n * 16 + (l & 15);
  short8 vh, vl;
#pragma unroll
  for (int j = 0; j < 8; ++j) {
    float v = W[(size_t)(d0 + j) * NE + e];
    short h = bf16bits(v);
    vh[j] = h;
    vl[j] = bf16bits(v - bf16tof(h));
  }
  wf[(size_t)((s * 4 + n) * 2 + 0) * 64 + l] = vh;
  wf[(size_t)((s * 4 + n) * 2 + 1) * 64 + l] = vl;
}

// ---- fused kernel: block = 16 tokens x 2048 k + softmax + top-2 ----
__global__ __launch_bounds__(256, 4) void router_fused(
    const float* __restrict__ x, const short8* __restrict__ wf,
    const float* __restrict__ b, float* __restrict__ out, int ntok) {
  __shared__ alignas(16) char smem[16 * TSTRIDE];  // 33024 B -> 4 blocks/CU
  const int tid = threadIdx.x, lane = tid & 63, kq = tid >> 6;
  const int g = lane & 15, r4 = lane >> 4;
  const int tok0 = blockIdx.x * 16;

  floatx4 acc[4];
#pragma unroll
  for (int n = 0; n < 4; ++n) acc[n] = (floatx4){0.f, 0.f, 0.f, 0.f};

#pragma unroll 1
  for (int chunk = 0; chunk < 4; ++chunk) {
    // ---- stage 16 rows x 2 KB (NT dwordx4 loads -> ds_write_b128) ----
    {
      const int row = kq * 4 + r4;
      const float* rp =
          x + (size_t)(tok0 + row) * DIM + chunk * 512 + g * 4;
      char* wb = smem + row * TSTRIDE + g * 16;
      floatx4 t[8];
#pragma unroll
      for (int p = 0; p < 8; ++p)
        t[p] = __builtin_nontemporal_load((const floatx4*)(rp + p * 64));
#pragma unroll
      for (int p = 0; p < 8; ++p) *(floatx4*)(wb + p * 256) = t[p];
    }
    __syncthreads();

    // wave kq computes k-range [kq*128,+128) of this chunk; NOT unrolled
#pragma unroll 1
    for (int step = 0; step < 4; ++step) {
      const int sg = chunk * 16 + kq * 4 + step;  // global 32-k step
      const short8* wp = wf + (size_t)sg * 512;
      short8 Wh[4], Wl[4];
#pragma unroll
      for (int n = 0; n < 4; ++n) {
        Wh[n] = wp[(n * 2 + 0) * 64 + lane];
        Wl[n] = wp[(n * 2 + 1) * 64 + lane];
      }
      // A-frag: m = lane&15 (token), k = step*32 + (lane>>4)*8 + j
      const char* ap = smem + g * TSTRIDE + kq * 512 + step * 128 + r4 * 32;
      floatx4 a0 = *(const floatx4*)ap;
      floatx4 a1 = *(const floatx4*)(ap + 16);
      short8 Ah, Al;
#pragma unroll
      for (int j = 0; j < 4; ++j) {
        short h = bf16bits(a0[j]);
        Ah[j] = h; Al[j] = bf16bits(a0[j] - bf16tof(h));
      }
#pragma unroll
      for (int j = 0; j < 4; ++j) {
        short h = bf16bits(a1[j]);
        Ah[4 + j] = h; Al[4 + j] = bf16bits(a1[j] - bf16tof(h));
      }
#pragma unroll
      for (int n = 0; n < 4; ++n) {
        acc[n] = __builtin_amdgcn_mfma_f32_16x16x32_bf16(Ah, Wh[n], acc[n], 0, 0, 0);
        acc[n] = __builtin_amdgcn_mfma_f32_16x16x32_bf16(Ah, Wl[n], acc[n], 0, 0, 0);
        acc[n] = __builtin_amdgcn_mfma_f32_16x16x32_bf16(Al, Wh[n], acc[n], 0, 0, 0);
      }
    }
    __syncthreads();  // tile reads done before next chunk's staging
  }

  // ---- cross-wave K reduction, b128: redt[kq][e][tok stride 20] ----
  float* redt = (float*)smem;                 // 4*64*20*4 = 20480 B
  float* lgt = (float*)(smem + 20480);        // 64*17*4  =  4352 B
#pragma unroll
  for (int n = 0; n < 4; ++n) {
    // acc[n][r]: token = r4*4+r, expert e = n*16+g  (C/D layout)
    *(floatx4*)(redt + ((size_t)kq * 64 + n * 16 + g) * 20 + r4 * 4) = acc[n];
  }
  __syncthreads();

  // sum 4 k-slices + bias -> lgt[e][tok stride 17]
  {
    const int e = tid >> 2, q = tid & 3;
    floatx4 s = (floatx4){0.f, 0.f, 0.f, 0.f};
#pragma unroll
    for (int k4 = 0; k4 < 4; ++k4)
      s += *(const floatx4*)(redt + ((size_t)k4 * 64 + e) * 20 + q * 4);
    const float be = b[e];
#pragma unroll
    for (int j = 0; j < 4; ++j) lgt[e * 17 + q * 4 + j] = s[j] + be;
  }
  __syncthreads();

  // ---- softmax + top-2 for the block's 16 tokens (wave 0 only) ----
  if (kq == 0) {
    const int t = lane & 15, er = lane >> 4;  // lane scans experts er*16..+15
    float lv[16];
    float v1 = -INFINITY, v2 = -INFINITY;
    int i1 = 0, i2 = 0;
#pragma unroll
    for (int i = 0; i < 16; ++i) {
      const int e = er * 16 + i;
      float v = lgt[e * 17 + t];
      lv[i] = v;
      if (v > v1) { v2 = v1; i2 = i1; v1 = v; i1 = e; }
      else if (v > v2) { v2 = v; i2 = e; }
    }
    // merge top-2 across the 4 expert-sublanes (ties -> lowest index)
#pragma unroll
    for (int off = 16; off < 64; off <<= 1) {
      float ov1 = __shfl_xor(v1, off, 64); int oi1 = __shfl_xor(i1, off, 64);
      float ov2 = __shfl_xor(v2, off, 64); int oi2 = __shfl_xor(i2, off, 64);
      bool aw = (v1 > ov1) || (v1 == ov1 && i1 < oi1);
      float nv1 = aw ? v1 : ov1; int ni1 = aw ? i1 : oi1;
      float c2v = aw ? ov1 : v1; int c2i = aw ? oi1 : i1;
      float w2v = aw ? v2 : ov2; int w2i = aw ? i2 : oi2;
      bool sw = (w2v > c2v) || (w2v == c2v && w2i < c2i);
      v2 = sw ? w2v : c2v; i2 = sw ? w2i : c2i;
      v1 = nv1; i1 = ni1;
    }
    float se = 0.f;
#pragma unroll
    for (int i = 0; i < 16; ++i) se += __expf(lv[i] - v1);
#pragma unroll
    for (int off = 16; off < 64; off <<= 1) se += __shfl_xor(se, off, 64);
    if (er == 0) {
      const int tok = tok0 + t;
      float2 idx = {(float)i1, (float)i2};
      float2 gv = {1.0f / se, __expf(v2 - v1) / se};
      *(float2*)(out + tok * 2) = idx;
      *(float2*)(out + ntok * 2 + tok * 2) = gv;
    }
  }
}

extern "C" void kernel_launch(void* const* d_in, const int* in_sizes, int n_in,
                              void* d_out, int out_size, void* d_ws, size_t ws_size,
                              hipStream_t stream) {
  const float* x = (const float*)d_in[0];
  const float* W = (const float*)d_in[1];
  const float* b = (const float*)d_in[2];
  float* out = (float*)d_out;
  const int ntok = in_sizes[0] / DIM;   // 16384
  short8* wf = (short8*)d_ws;           // 512 KB W fragments

  wprep_kernel<<<256, 64, 0, stream>>>(W, wf);
  router_fused<<<ntok / 16, 256, 0, stream>>>(x, wf, b, out, ntok);
}